// Round 5
// baseline (2072.791 us; speedup 1.0000x reference)
//
#include <hip/hip_runtime.h>

#define N_RAYS 16384
#define NSAMP  96
#define GD 128
#define GH 128
#define GW 128
#define C_IN  32
#define C_HID 32
#define C_OUT 16
#define M_PTS (N_RAYS * NSAMP)       // 1,572,864 (divisible by 256)
#define TPA 16                        // tiles per axis (128/8)
#define NTILES (TPA*TPA*TPA)          // 4096
#define TW 8                          // tile width (voxels)
#define TVOX (TW*TW*TW)               // 512 voxels per tile

__device__ __forceinline__ int clampi(int v, int hi) { return min(max(v, 0), hi); }

struct TileSpan { int txa, txb, tya, tyb, tza, tzb; };
__device__ __forceinline__ TileSpan tile_span(int X, int Y, int Z) {
    TileSpan s;
    s.txa = clampi(X,   GW-1) >> 3;  s.txb = clampi(X+1, GW-1) >> 3;
    s.tya = clampi(Y,   GH-1) >> 3;  s.tyb = clampi(Y+1, GH-1) >> 3;
    s.tza = clampi(Z,   GD-1) >> 3;  s.tzb = clampi(Z+1, GD-1) >> 3;
    return s;
}

// ============================================================================
// K1: per-point gather + MLP. Stores o[16] (planar float4) + frac/key, and
// accumulates per-tile point counts (LDS histogram -> global atomicAdd).
// ============================================================================
__global__ __launch_bounds__(256) void k1_point(
    const float* __restrict__ origins, const float* __restrict__ dirs,
    const float* __restrict__ nearv,   const float* __restrict__ farv,
    const float* __restrict__ enc,     const int*   __restrict__ gidx,
    const float* __restrict__ grid,    const float* __restrict__ W0,
    const float* __restrict__ b0,      const float* __restrict__ W1,
    const float* __restrict__ b1,
    float4* __restrict__ pf, float4* __restrict__ po, unsigned* __restrict__ counts)
{
    __shared__ unsigned lcnt[NTILES];
    for (int i = threadIdx.x; i < NTILES; i += 256) lcnt[i] = 0;
    __syncthreads();

    int pid = blockIdx.x * 256 + threadIdx.x;     // always < M_PTS (exact grid)
    int ray = pid / NSAMP;
    int s   = pid - ray * NSAMP;

    float nr = nearv[ray], fr = farv[ray];
    float t  = nr + (fr - nr) * ((float)s * (1.0f / (NSAMP - 1)));
    float px = fmaf(t, dirs[ray*3+0], origins[ray*3+0]);
    float py = fmaf(t, dirs[ray*3+1], origins[ray*3+1]);
    float pz = fmaf(t, dirs[ray*3+2], origins[ray*3+2]);
    int   b  = gidx[ray];

    float cx = ((px + 1.0f) * (float)GW - 1.0f) * 0.5f;
    float cy = ((py + 1.0f) * (float)GH - 1.0f) * 0.5f;
    float cz = ((pz + 1.0f) * (float)GD - 1.0f) * 0.5f;
    float fxf = floorf(cx), fyf = floorf(cy), fzf = floorf(cz);
    float fx = cx - fxf, fy = cy - fyf, fz = cz - fzf;
    int X = (int)fxf, Y = (int)fyf, Z = (int)fzf;

    // ---- trilinear gather (feat starts at ray encoding) ----
    float feat[C_IN];
    {
        const float4* e4 = (const float4*)(enc + (size_t)ray * C_IN);
        #pragma unroll
        for (int q = 0; q < C_IN/4; ++q) {
            float4 v = e4[q];
            feat[4*q+0] = v.x; feat[4*q+1] = v.y; feat[4*q+2] = v.z; feat[4*q+3] = v.w;
        }
    }
    int gx[2] = { clampi(X, GW-1), clampi(X+1, GW-1) };
    int gy[2] = { clampi(Y, GH-1), clampi(Y+1, GH-1) };
    int gz[2] = { clampi(Z, GD-1), clampi(Z+1, GD-1) };
    float wxa[2] = { 1.0f - fx, fx };
    float wya[2] = { 1.0f - fy, fy };
    float wza[2] = { 1.0f - fz, fz };
    #pragma unroll
    for (int dz = 0; dz < 2; ++dz)
    #pragma unroll
    for (int dy = 0; dy < 2; ++dy)
    #pragma unroll
    for (int dx = 0; dx < 2; ++dx) {
        float w = wza[dz] * wya[dy] * wxa[dx];
        size_t flat = ((((size_t)b * GD + gz[dz]) * GH + gy[dy]) * GW + gx[dx]) * C_IN;
        const float4* g4 = (const float4*)(grid + flat);
        #pragma unroll
        for (int q = 0; q < C_IN/4; ++q) {
            float4 v = g4[q];
            feat[4*q+0] = fmaf(w, v.x, feat[4*q+0]);
            feat[4*q+1] = fmaf(w, v.y, feat[4*q+1]);
            feat[4*q+2] = fmaf(w, v.z, feat[4*q+2]);
            feat[4*q+3] = fmaf(w, v.w, feat[4*q+3]);
        }
    }

    // ---- MLP (weights wave-uniform -> scalar loads) ----
    float h[C_HID];
    #pragma unroll
    for (int j = 0; j < C_HID; ++j) h[j] = b0[j];
    #pragma unroll
    for (int i = 0; i < C_IN; ++i) {
        float xi = feat[i];
        #pragma unroll
        for (int j = 0; j < C_HID; ++j) h[j] = fmaf(xi, W0[i*C_HID + j], h[j]);
    }
    #pragma unroll
    for (int j = 0; j < C_HID; ++j) h[j] = fmaxf(h[j], 0.0f);

    float o[C_OUT];
    #pragma unroll
    for (int j = 0; j < C_OUT; ++j) o[j] = b1[j];
    #pragma unroll
    for (int i = 0; i < C_HID; ++i) {
        float hi = h[i];
        #pragma unroll
        for (int j = 0; j < C_OUT; ++j) o[j] = fmaf(hi, W1[i*C_OUT + j], o[j]);
    }

    // ---- store point record (planar, coalesced) ----
    unsigned key = ((unsigned)(X + 256) & 511u)
                 | (((unsigned)(Y + 256) & 511u) << 9)
                 | (((unsigned)(Z + 256) & 511u) << 18);
    pf[pid] = make_float4(fx, fy, fz, __uint_as_float(key));
    #pragma unroll
    for (int q = 0; q < 4; ++q)
        po[(size_t)q * M_PTS + pid] = make_float4(o[4*q+0], o[4*q+1], o[4*q+2], o[4*q+3]);

    // ---- count touched tiles ----
    TileSpan ts = tile_span(X, Y, Z);
    #pragma unroll
    for (int ez = 0; ez < 2; ++ez) {
        if (ez && ts.tzb == ts.tza) continue;
        #pragma unroll
        for (int ey = 0; ey < 2; ++ey) {
            if (ey && ts.tyb == ts.tya) continue;
            #pragma unroll
            for (int ex = 0; ex < 2; ++ex) {
                if (ex && ts.txb == ts.txa) continue;
                int tt = ((ts.tza + ez) * TPA + (ts.tya + ey)) * TPA + (ts.txa + ex);
                atomicAdd(&lcnt[tt], 1u);
            }
        }
    }
    __syncthreads();
    for (int i = threadIdx.x; i < NTILES; i += 256)
        if (lcnt[i]) atomicAdd(&counts[i], lcnt[i]);
}

// ============================================================================
// K2: exclusive scan of 4096 tile counts (single block, simple & correct).
// ============================================================================
__global__ __launch_bounds__(256) void k2_scan(
    const unsigned* __restrict__ counts,
    unsigned* __restrict__ offsets, unsigned* __restrict__ alloc)
{
    __shared__ unsigned psum[256];
    int tid = threadIdx.x;
    unsigned base = tid * 16;
    unsigned ssum = 0;
    for (int i = 0; i < 16; ++i) ssum += counts[base + i];
    psum[tid] = ssum;
    __syncthreads();
    if (tid == 0) {
        unsigned r = 0;
        for (int i = 0; i < 256; ++i) { unsigned v = psum[i]; psum[i] = r; r += v; }
    }
    __syncthreads();
    unsigned run = psum[tid];
    for (int i = 0; i < 16; ++i) {
        unsigned v = counts[base + i];
        offsets[base + i] = run;
        alloc[base + i]   = run;
        run += v;
    }
}

// ============================================================================
// K3: scatter point indices into per-tile segments. Block-local LDS histogram
// + rank, one global atomicAdd per (block, nonzero tile) for segment alloc.
// ============================================================================
__global__ __launch_bounds__(256) void k3_scatter(
    const float4* __restrict__ pf, unsigned* __restrict__ alloc,
    unsigned* __restrict__ entries)
{
    __shared__ unsigned lcnt[NTILES];
    __shared__ unsigned lbase[NTILES];
    for (int i = threadIdx.x; i < NTILES; i += 256) lcnt[i] = 0;
    __syncthreads();

    int pid = blockIdx.x * 256 + threadIdx.x;
    float4 f = pf[pid];
    unsigned key = __float_as_uint(f.w);
    int X = (int)(key & 511u) - 256;
    int Y = (int)((key >> 9) & 511u) - 256;
    int Z = (int)((key >> 18) & 511u) - 256;
    TileSpan ts = tile_span(X, Y, Z);

    unsigned rnk[2][2][2];
    #pragma unroll
    for (int ez = 0; ez < 2; ++ez) {
        bool okz = (ez == 0) || (ts.tzb > ts.tza);
        #pragma unroll
        for (int ey = 0; ey < 2; ++ey) {
            bool oky = (ey == 0) || (ts.tyb > ts.tya);
            #pragma unroll
            for (int ex = 0; ex < 2; ++ex) {
                bool okx = (ex == 0) || (ts.txb > ts.txa);
                if (okz && oky && okx) {
                    int tt = ((ts.tza + ez) * TPA + (ts.tya + ey)) * TPA + (ts.txa + ex);
                    rnk[ez][ey][ex] = atomicAdd(&lcnt[tt], 1u);
                }
            }
        }
    }
    __syncthreads();
    for (int i = threadIdx.x; i < NTILES; i += 256)
        if (lcnt[i]) lbase[i] = atomicAdd(&alloc[i], lcnt[i]);
    __syncthreads();
    #pragma unroll
    for (int ez = 0; ez < 2; ++ez) {
        bool okz = (ez == 0) || (ts.tzb > ts.tza);
        #pragma unroll
        for (int ey = 0; ey < 2; ++ey) {
            bool oky = (ey == 0) || (ts.tyb > ts.tya);
            #pragma unroll
            for (int ex = 0; ex < 2; ++ex) {
                bool okx = (ex == 0) || (ts.txb > ts.txa);
                if (okz && oky && okx) {
                    int tt = ((ts.tza + ez) * TPA + (ts.tya + ey)) * TPA + (ts.txa + ex);
                    entries[lbase[tt] + rnk[ez][ey][ex]] = (unsigned)pid;
                }
            }
        }
    }
}

// ============================================================================
// K4: one block per tile. CHANNEL-MAJOR LDS accumulator acc[c*512 + v]:
// each ds_add instruction (fixed c, lanes vary v) spreads across banks
// (bank = v mod 32) instead of the voxel-major layout's 2-bank pileup.
// The 16 per-corner ds_adds share one address reg + c*2048 offset imms.
// Writeback transposes from LDS (4 ds_read per float4; tiny cost).
// ============================================================================
__global__ __launch_bounds__(256) void k4_accum(
    const float4* __restrict__ pf, const float4* __restrict__ po,
    const unsigned* __restrict__ entries, const unsigned* __restrict__ offsets,
    const unsigned* __restrict__ alloc, float* __restrict__ out)
{
    __shared__ float acc[C_OUT * TVOX];    // [16][512] channel-major, 32 KB
    int t  = blockIdx.x;
    int tx = t & (TPA-1), ty = (t >> 4) & (TPA-1), tz = t >> 8;
    int ox = tx * TW, oy = ty * TW, oz = tz * TW;

    for (int i = threadIdx.x; i < C_OUT * TVOX; i += 256) acc[i] = 0.0f;
    __syncthreads();

    unsigned e0 = offsets[t], e1 = alloc[t];
    for (unsigned e = e0 + threadIdx.x; e < e1; e += 256) {
        unsigned p = entries[e];
        float4 f = pf[p];
        unsigned key = __float_as_uint(f.w);
        int X = (int)(key & 511u) - 256;
        int Y = (int)((key >> 9) & 511u) - 256;
        int Z = (int)((key >> 18) & 511u) - 256;
        float wxa[2] = { 1.0f - f.x, f.x };
        float wya[2] = { 1.0f - f.y, f.y };
        float wza[2] = { 1.0f - f.z, f.z };
        float4 o0 = po[p];
        float4 o1 = po[(size_t)M_PTS + p];
        float4 o2 = po[2*(size_t)M_PTS + p];
        float4 o3 = po[3*(size_t)M_PTS + p];
        float o[C_OUT] = { o0.x,o0.y,o0.z,o0.w, o1.x,o1.y,o1.z,o1.w,
                           o2.x,o2.y,o2.z,o2.w, o3.x,o3.y,o3.z,o3.w };
        #pragma unroll
        for (int dz = 0; dz < 2; ++dz) {
            int vz = clampi(Z + dz, GD-1);
            bool inz = (vz >= oz) && (vz < oz + TW);
            #pragma unroll
            for (int dy = 0; dy < 2; ++dy) {
                int vy = clampi(Y + dy, GH-1);
                bool iny = (vy >= oy) && (vy < oy + TW);
                #pragma unroll
                for (int dx = 0; dx < 2; ++dx) {
                    int vx = clampi(X + dx, GW-1);
                    bool inx = (vx >= ox) && (vx < ox + TW);
                    if (inz && iny && inx) {
                        int v = (((vz - oz) * TW + (vy - oy)) * TW + (vx - ox));
                        float w = wza[dz] * wya[dy] * wxa[dx];
                        #pragma unroll
                        for (int c = 0; c < C_OUT; ++c)
                            atomicAdd(&acc[c * TVOX + v], w * o[c]);
                    }
                }
            }
        }
    }
    __syncthreads();

    // transpose writeback: out[(voxel)][c] float4 from acc[c][voxel]
    for (int i = threadIdx.x; i < (TVOX * C_OUT) / 4; i += 256) {
        int v  = i >> 2;            // voxel 0..511
        int cq = (i & 3) * 4;       // channel quad base
        float4 r = make_float4(acc[(cq+0) * TVOX + v], acc[(cq+1) * TVOX + v],
                               acc[(cq+2) * TVOX + v], acc[(cq+3) * TVOX + v]);
        int vx = v & (TW-1), vy = (v >> 3) & (TW-1), vz = v >> 6;
        size_t oaddr = ((((size_t)(oz + vz)) * GH + (oy + vy)) * GW + (ox + vx)) * C_OUT + cq;
        *(float4*)(out + oaddr) = r;
    }
}

// ============================================================================
// Fallback (round-3 fused kernel) if workspace is too small.
// ============================================================================
#define SEGS   8
#define SEGLEN (NSAMP / SEGS)
#define NTHREADS (N_RAYS * SEGS)

__global__ __launch_bounds__(256, 2) void splat_seg_kernel(
    const float* __restrict__ origins, const float* __restrict__ dirs,
    const float* __restrict__ nearv,   const float* __restrict__ farv,
    const float* __restrict__ enc,     const int*   __restrict__ gidx,
    const float* __restrict__ grid,    const float* __restrict__ W0,
    const float* __restrict__ b0,      const float* __restrict__ W1,
    const float* __restrict__ b1,      float* __restrict__ out)
{
    int tid = blockIdx.x * blockDim.x + threadIdx.x;
    if (tid >= NTHREADS) return;
    int ray = tid / SEGS;
    int seg = tid - ray * SEGS;
    float nr = nearv[ray], fr = farv[ray];
    float ox = origins[3*ray+0], oy = origins[3*ray+1], oz = origins[3*ray+2];
    float rdx = dirs[3*ray+0],   rdy = dirs[3*ray+1],   rdz = dirs[3*ray+2];
    int   b  = gidx[ray];
    float accv[8][C_OUT];
    #pragma unroll
    for (int sl = 0; sl < 8; ++sl)
        #pragma unroll
        for (int c = 0; c < C_OUT; ++c) accv[sl][c] = 0.0f;
    int Xp = 0, Yp = 0, Zp = 0;
    #pragma unroll 1
    for (int k = 0; k < SEGLEN; ++k) {
        int s = seg * SEGLEN + k;
        float t  = nr + (fr - nr) * ((float)s * (1.0f / (NSAMP - 1)));
        float px = fmaf(t, rdx, ox);
        float py = fmaf(t, rdy, oy);
        float pz = fmaf(t, rdz, oz);
        float cx = ((px + 1.0f) * (float)GW - 1.0f) * 0.5f;
        float cy = ((py + 1.0f) * (float)GH - 1.0f) * 0.5f;
        float cz = ((pz + 1.0f) * (float)GD - 1.0f) * 0.5f;
        float fxf = floorf(cx), fyf = floorf(cy), fzf = floorf(cz);
        float fx = cx - fxf, fy = cy - fyf, fz = cz - fzf;
        int X = (int)fxf, Y = (int)fyf, Z = (int)fzf;
        if (k == 0) { Xp = X; Yp = Y; Zp = Z; }
        else if (X != Xp || Y != Yp || Z != Zp) {
            bool fXm[2], fYm[2], fZm[2];
            int  vx[2], vy[2], vz[2];
            #pragma unroll
            for (int p = 0; p < 2; ++p) {
                int xo = Xp + ((Xp ^ p) & 1), xn = X + ((X ^ p) & 1);
                fXm[p] = (xo != xn);  vx[p] = clampi(xo, GW-1);
                int yo = Yp + ((Yp ^ p) & 1), yn = Y + ((Y ^ p) & 1);
                fYm[p] = (yo != yn);  vy[p] = clampi(yo, GH-1);
                int zo = Zp + ((Zp ^ p) & 1), zn = Z + ((Z ^ p) & 1);
                fZm[p] = (zo != zn);  vz[p] = clampi(zo, GD-1);
            }
            #pragma unroll
            for (int pxi = 0; pxi < 2; ++pxi)
            #pragma unroll
            for (int pyi = 0; pyi < 2; ++pyi)
            #pragma unroll
            for (int pzi = 0; pzi < 2; ++pzi) {
                const int sl = pxi*4 + pyi*2 + pzi;
                if (fXm[pxi] | fYm[pyi] | fZm[pzi]) {
                    size_t flat = ((((size_t)b * GD + vz[pzi]) * GH + vy[pyi]) * GW + vx[pxi]) * C_OUT;
                    float* op = out + flat;
                    #pragma unroll
                    for (int c = 0; c < C_OUT; ++c) { atomicAdd(op + c, accv[sl][c]); accv[sl][c] = 0.0f; }
                }
            }
            Xp = X; Yp = Y; Zp = Z;
        }
        float feat[C_IN];
        {
            const float4* e4 = (const float4*)(enc + (size_t)ray * C_IN);
            #pragma unroll
            for (int q = 0; q < C_IN/4; ++q) {
                float4 v = e4[q];
                feat[4*q+0] = v.x; feat[4*q+1] = v.y; feat[4*q+2] = v.z; feat[4*q+3] = v.w;
            }
        }
        int gx[2] = { clampi(X, GW-1), clampi(X+1, GW-1) };
        int gy[2] = { clampi(Y, GH-1), clampi(Y+1, GH-1) };
        int gz[2] = { clampi(Z, GD-1), clampi(Z+1, GD-1) };
        float wxa[2] = { 1.0f - fx, fx };
        float wya[2] = { 1.0f - fy, fy };
        float wza[2] = { 1.0f - fz, fz };
        #pragma unroll
        for (int dz = 0; dz < 2; ++dz)
        #pragma unroll
        for (int dy = 0; dy < 2; ++dy)
        #pragma unroll
        for (int dx = 0; dx < 2; ++dx) {
            float w = wza[dz] * wya[dy] * wxa[dx];
            size_t flat = ((((size_t)b * GD + gz[dz]) * GH + gy[dy]) * GW + gx[dx]) * C_IN;
            const float4* g4 = (const float4*)(grid + flat);
            #pragma unroll
            for (int q = 0; q < C_IN/4; ++q) {
                float4 v = g4[q];
                feat[4*q+0] = fmaf(w, v.x, feat[4*q+0]);
                feat[4*q+1] = fmaf(w, v.y, feat[4*q+1]);
                feat[4*q+2] = fmaf(w, v.z, feat[4*q+2]);
                feat[4*q+3] = fmaf(w, v.w, feat[4*q+3]);
            }
        }
        float h[C_HID];
        #pragma unroll
        for (int j = 0; j < C_HID; ++j) h[j] = b0[j];
        #pragma unroll
        for (int i = 0; i < C_IN; ++i) {
            float xi = feat[i];
            #pragma unroll
            for (int j = 0; j < C_HID; ++j) h[j] = fmaf(xi, W0[i*C_HID + j], h[j]);
        }
        #pragma unroll
        for (int j = 0; j < C_HID; ++j) h[j] = fmaxf(h[j], 0.0f);
        float o[C_OUT];
        #pragma unroll
        for (int j = 0; j < C_OUT; ++j) o[j] = b1[j];
        #pragma unroll
        for (int i = 0; i < C_HID; ++i) {
            float hi = h[i];
            #pragma unroll
            for (int j = 0; j < C_OUT; ++j) o[j] = fmaf(hi, W1[i*C_OUT + j], o[j]);
        }
        float wxs[2], wys[2], wzs[2];
        #pragma unroll
        for (int p = 0; p < 2; ++p) {
            wxs[p] = ((X & 1) == p) ? (1.0f - fx) : fx;
            wys[p] = ((Y & 1) == p) ? (1.0f - fy) : fy;
            wzs[p] = ((Z & 1) == p) ? (1.0f - fz) : fz;
        }
        #pragma unroll
        for (int pxi = 0; pxi < 2; ++pxi)
        #pragma unroll
        for (int pyi = 0; pyi < 2; ++pyi)
        #pragma unroll
        for (int pzi = 0; pzi < 2; ++pzi) {
            const int sl = pxi*4 + pyi*2 + pzi;
            float w = wxs[pxi] * wys[pyi] * wzs[pzi];
            #pragma unroll
            for (int c = 0; c < C_OUT; ++c) accv[sl][c] = fmaf(w, o[c], accv[sl][c]);
        }
    }
    #pragma unroll
    for (int pxi = 0; pxi < 2; ++pxi)
    #pragma unroll
    for (int pyi = 0; pyi < 2; ++pyi)
    #pragma unroll
    for (int pzi = 0; pzi < 2; ++pzi) {
        const int sl = pxi*4 + pyi*2 + pzi;
        int vx = clampi(Xp + ((Xp ^ pxi) & 1), GW-1);
        int vy = clampi(Yp + ((Yp ^ pyi) & 1), GH-1);
        int vz = clampi(Zp + ((Zp ^ pzi) & 1), GD-1);
        size_t flat = ((((size_t)b * GD + vz) * GH + vy) * GW + vx) * C_OUT;
        float* op = out + flat;
        #pragma unroll
        for (int c = 0; c < C_OUT; ++c) atomicAdd(op + c, accv[sl][c]);
    }
}

// ============================================================================
extern "C" void kernel_launch(void* const* d_in, const int* in_sizes, int n_in,
                              void* d_out, int out_size, void* d_ws, size_t ws_size,
                              hipStream_t stream) {
    const float* origins = (const float*)d_in[0];
    const float* dirs    = (const float*)d_in[1];
    const float* nearv   = (const float*)d_in[2];
    const float* farv    = (const float*)d_in[3];
    const float* enc     = (const float*)d_in[4];
    const int*   gidx    = (const int*)  d_in[5];
    const float* grid    = (const float*)d_in[6];
    const float* W0      = (const float*)d_in[7];
    const float* b0      = (const float*)d_in[8];
    const float* W1      = (const float*)d_in[9];
    const float* b1      = (const float*)d_in[10];
    float* out = (float*)d_out;

    const size_t PF_B = (size_t)M_PTS * 16;         // 25,165,824
    const size_t PO_B = (size_t)M_PTS * 64;         // 100,663,296
    const size_t EN_B = (size_t)M_PTS * 8 * 4;      // 50,331,648 (hard bound)
    const size_t CT_B = (size_t)NTILES * 4;
    const size_t NEED = PF_B + PO_B + EN_B + 3 * CT_B;

    if (ws_size < NEED) {
        // fallback: fused register-merged scatter (round-3 path)
        hipMemsetAsync(out, 0, (size_t)out_size * sizeof(float), stream);
        splat_seg_kernel<<<NTHREADS/256, 256, 0, stream>>>(
            origins, dirs, nearv, farv, enc, gidx, grid, W0, b0, W1, b1, out);
        return;
    }

    char* w = (char*)d_ws;
    float4*   pf      = (float4*)   w;              w += PF_B;
    float4*   po      = (float4*)   w;              w += PO_B;
    unsigned* entries = (unsigned*) w;              w += EN_B;
    unsigned* counts  = (unsigned*) w;              w += CT_B;
    unsigned* offsets = (unsigned*) w;              w += CT_B;
    unsigned* alloc   = (unsigned*) w;              w += CT_B;

    hipMemsetAsync(counts, 0, CT_B, stream);
    k1_point<<<M_PTS/256, 256, 0, stream>>>(origins, dirs, nearv, farv, enc, gidx,
                                            grid, W0, b0, W1, b1, pf, po, counts);
    k2_scan<<<1, 256, 0, stream>>>(counts, offsets, alloc);
    k3_scatter<<<M_PTS/256, 256, 0, stream>>>(pf, alloc, entries);
    k4_accum<<<NTILES, 256, 0, stream>>>(pf, po, entries, offsets, alloc, out);
    // K4 writes every output voxel densely -> no output memset needed.
}

// Round 6
// 1052.738 us; speedup vs baseline: 1.9690x; 1.9690x over previous
//
#include <hip/hip_runtime.h>

#define N_RAYS 16384
#define NSAMP  96
#define GD 128
#define GH 128
#define GW 128
#define C_IN  32
#define C_HID 32
#define C_OUT 16
#define M_PTS (N_RAYS * NSAMP)       // 1,572,864 (divisible by 256)
#define TPA 16                        // tiles per axis (128/8)
#define NTILES (TPA*TPA*TPA)          // 4096
#define TW 8                          // tile width (voxels)
#define TVOX (TW*TW*TW)               // 512 voxels per tile
#define CHUNK 256                     // entries staged per K4 inner pass

__device__ __forceinline__ int clampi(int v, int hi) { return min(max(v, 0), hi); }

struct TileSpan { int txa, txb, tya, tyb, tza, tzb; };
__device__ __forceinline__ TileSpan tile_span(int X, int Y, int Z) {
    TileSpan s;
    s.txa = clampi(X,   GW-1) >> 3;  s.txb = clampi(X+1, GW-1) >> 3;
    s.tya = clampi(Y,   GH-1) >> 3;  s.tyb = clampi(Y+1, GH-1) >> 3;
    s.tza = clampi(Z,   GD-1) >> 3;  s.tzb = clampi(Z+1, GD-1) >> 3;
    return s;
}

// ============================================================================
// K1: per-point gather + MLP. Stores o[16] (planar float4) + frac/key, and
// accumulates per-tile point counts (LDS histogram -> global atomicAdd).
// ============================================================================
__global__ __launch_bounds__(256) void k1_point(
    const float* __restrict__ origins, const float* __restrict__ dirs,
    const float* __restrict__ nearv,   const float* __restrict__ farv,
    const float* __restrict__ enc,     const int*   __restrict__ gidx,
    const float* __restrict__ grid,    const float* __restrict__ W0,
    const float* __restrict__ b0,      const float* __restrict__ W1,
    const float* __restrict__ b1,
    float4* __restrict__ pf, float4* __restrict__ po, unsigned* __restrict__ counts)
{
    __shared__ unsigned lcnt[NTILES];
    for (int i = threadIdx.x; i < NTILES; i += 256) lcnt[i] = 0;
    __syncthreads();

    int pid = blockIdx.x * 256 + threadIdx.x;     // always < M_PTS (exact grid)
    int ray = pid / NSAMP;
    int s   = pid - ray * NSAMP;

    float nr = nearv[ray], fr = farv[ray];
    float t  = nr + (fr - nr) * ((float)s * (1.0f / (NSAMP - 1)));
    float px = fmaf(t, dirs[ray*3+0], origins[ray*3+0]);
    float py = fmaf(t, dirs[ray*3+1], origins[ray*3+1]);
    float pz = fmaf(t, dirs[ray*3+2], origins[ray*3+2]);
    int   b  = gidx[ray];

    float cx = ((px + 1.0f) * (float)GW - 1.0f) * 0.5f;
    float cy = ((py + 1.0f) * (float)GH - 1.0f) * 0.5f;
    float cz = ((pz + 1.0f) * (float)GD - 1.0f) * 0.5f;
    float fxf = floorf(cx), fyf = floorf(cy), fzf = floorf(cz);
    float fx = cx - fxf, fy = cy - fyf, fz = cz - fzf;
    int X = (int)fxf, Y = (int)fyf, Z = (int)fzf;

    // ---- trilinear gather (feat starts at ray encoding) ----
    float feat[C_IN];
    {
        const float4* e4 = (const float4*)(enc + (size_t)ray * C_IN);
        #pragma unroll
        for (int q = 0; q < C_IN/4; ++q) {
            float4 v = e4[q];
            feat[4*q+0] = v.x; feat[4*q+1] = v.y; feat[4*q+2] = v.z; feat[4*q+3] = v.w;
        }
    }
    int gx[2] = { clampi(X, GW-1), clampi(X+1, GW-1) };
    int gy[2] = { clampi(Y, GH-1), clampi(Y+1, GH-1) };
    int gz[2] = { clampi(Z, GD-1), clampi(Z+1, GD-1) };
    float wxa[2] = { 1.0f - fx, fx };
    float wya[2] = { 1.0f - fy, fy };
    float wza[2] = { 1.0f - fz, fz };
    #pragma unroll
    for (int dz = 0; dz < 2; ++dz)
    #pragma unroll
    for (int dy = 0; dy < 2; ++dy)
    #pragma unroll
    for (int dx = 0; dx < 2; ++dx) {
        float w = wza[dz] * wya[dy] * wxa[dx];
        size_t flat = ((((size_t)b * GD + gz[dz]) * GH + gy[dy]) * GW + gx[dx]) * C_IN;
        const float4* g4 = (const float4*)(grid + flat);
        #pragma unroll
        for (int q = 0; q < C_IN/4; ++q) {
            float4 v = g4[q];
            feat[4*q+0] = fmaf(w, v.x, feat[4*q+0]);
            feat[4*q+1] = fmaf(w, v.y, feat[4*q+1]);
            feat[4*q+2] = fmaf(w, v.z, feat[4*q+2]);
            feat[4*q+3] = fmaf(w, v.w, feat[4*q+3]);
        }
    }

    // ---- MLP (weights wave-uniform -> scalar loads) ----
    float h[C_HID];
    #pragma unroll
    for (int j = 0; j < C_HID; ++j) h[j] = b0[j];
    #pragma unroll
    for (int i = 0; i < C_IN; ++i) {
        float xi = feat[i];
        #pragma unroll
        for (int j = 0; j < C_HID; ++j) h[j] = fmaf(xi, W0[i*C_HID + j], h[j]);
    }
    #pragma unroll
    for (int j = 0; j < C_HID; ++j) h[j] = fmaxf(h[j], 0.0f);

    float o[C_OUT];
    #pragma unroll
    for (int j = 0; j < C_OUT; ++j) o[j] = b1[j];
    #pragma unroll
    for (int i = 0; i < C_HID; ++i) {
        float hi = h[i];
        #pragma unroll
        for (int j = 0; j < C_OUT; ++j) o[j] = fmaf(hi, W1[i*C_OUT + j], o[j]);
    }

    // ---- store point record (planar, coalesced) ----
    unsigned key = ((unsigned)(X + 256) & 511u)
                 | (((unsigned)(Y + 256) & 511u) << 9)
                 | (((unsigned)(Z + 256) & 511u) << 18);
    pf[pid] = make_float4(fx, fy, fz, __uint_as_float(key));
    #pragma unroll
    for (int q = 0; q < 4; ++q)
        po[(size_t)q * M_PTS + pid] = make_float4(o[4*q+0], o[4*q+1], o[4*q+2], o[4*q+3]);

    // ---- count touched tiles ----
    TileSpan ts = tile_span(X, Y, Z);
    #pragma unroll
    for (int ez = 0; ez < 2; ++ez) {
        if (ez && ts.tzb == ts.tza) continue;
        #pragma unroll
        for (int ey = 0; ey < 2; ++ey) {
            if (ey && ts.tyb == ts.tya) continue;
            #pragma unroll
            for (int ex = 0; ex < 2; ++ex) {
                if (ex && ts.txb == ts.txa) continue;
                int tt = ((ts.tza + ez) * TPA + (ts.tya + ey)) * TPA + (ts.txa + ex);
                atomicAdd(&lcnt[tt], 1u);
            }
        }
    }
    __syncthreads();
    for (int i = threadIdx.x; i < NTILES; i += 256)
        if (lcnt[i]) atomicAdd(&counts[i], lcnt[i]);
}

// ============================================================================
// K2: exclusive scan of 4096 tile counts (single block, simple & correct).
// ============================================================================
__global__ __launch_bounds__(256) void k2_scan(
    const unsigned* __restrict__ counts,
    unsigned* __restrict__ offsets, unsigned* __restrict__ alloc)
{
    __shared__ unsigned psum[256];
    int tid = threadIdx.x;
    unsigned base = tid * 16;
    unsigned ssum = 0;
    for (int i = 0; i < 16; ++i) ssum += counts[base + i];
    psum[tid] = ssum;
    __syncthreads();
    if (tid == 0) {
        unsigned r = 0;
        for (int i = 0; i < 256; ++i) { unsigned v = psum[i]; psum[i] = r; r += v; }
    }
    __syncthreads();
    unsigned run = psum[tid];
    for (int i = 0; i < 16; ++i) {
        unsigned v = counts[base + i];
        offsets[base + i] = run;
        alloc[base + i]   = run;
        run += v;
    }
}

// ============================================================================
// K3: scatter point indices into per-tile segments. Block-local LDS histogram
// + rank, one global atomicAdd per (block, nonzero tile) for segment alloc.
// ============================================================================
__global__ __launch_bounds__(256) void k3_scatter(
    const float4* __restrict__ pf, unsigned* __restrict__ alloc,
    unsigned* __restrict__ entries)
{
    __shared__ unsigned lcnt[NTILES];
    __shared__ unsigned lbase[NTILES];
    for (int i = threadIdx.x; i < NTILES; i += 256) lcnt[i] = 0;
    __syncthreads();

    int pid = blockIdx.x * 256 + threadIdx.x;
    float4 f = pf[pid];
    unsigned key = __float_as_uint(f.w);
    int X = (int)(key & 511u) - 256;
    int Y = (int)((key >> 9) & 511u) - 256;
    int Z = (int)((key >> 18) & 511u) - 256;
    TileSpan ts = tile_span(X, Y, Z);

    unsigned rnk[2][2][2];
    #pragma unroll
    for (int ez = 0; ez < 2; ++ez) {
        bool okz = (ez == 0) || (ts.tzb > ts.tza);
        #pragma unroll
        for (int ey = 0; ey < 2; ++ey) {
            bool oky = (ey == 0) || (ts.tyb > ts.tya);
            #pragma unroll
            for (int ex = 0; ex < 2; ++ex) {
                bool okx = (ex == 0) || (ts.txb > ts.txa);
                if (okz && oky && okx) {
                    int tt = ((ts.tza + ez) * TPA + (ts.tya + ey)) * TPA + (ts.txa + ex);
                    rnk[ez][ey][ex] = atomicAdd(&lcnt[tt], 1u);
                }
            }
        }
    }
    __syncthreads();
    for (int i = threadIdx.x; i < NTILES; i += 256)
        if (lcnt[i]) lbase[i] = atomicAdd(&alloc[i], lcnt[i]);
    __syncthreads();
    #pragma unroll
    for (int ez = 0; ez < 2; ++ez) {
        bool okz = (ez == 0) || (ts.tzb > ts.tza);
        #pragma unroll
        for (int ey = 0; ey < 2; ++ey) {
            bool oky = (ey == 0) || (ts.tyb > ts.tya);
            #pragma unroll
            for (int ex = 0; ex < 2; ++ex) {
                bool okx = (ex == 0) || (ts.txb > ts.txa);
                if (okz && oky && okx) {
                    int tt = ((ts.tza + ez) * TPA + (ts.tya + ey)) * TPA + (ts.txa + ex);
                    entries[lbase[tt] + rnk[ez][ey][ex]] = (unsigned)pid;
                }
            }
        }
    }
}

// ============================================================================
// K4 (REWRITTEN): broadcast-gather, zero LDS atomics. One block per tile.
// Stage CHUNK entries into LDS (coalesced), then every thread scans the
// chunk: uniform-index LDS reads broadcast to all lanes (free), each thread
// tests its 2 owned voxels against the entry's stencil and accumulates into
// REGISTERS. Dense float4 writeback (also replaces the output memset).
// Border-clamped corners that collapse onto one voxel sum both weights.
// ============================================================================
__global__ __launch_bounds__(256) void k4_accum(
    const float4* __restrict__ pf, const float4* __restrict__ po,
    const unsigned* __restrict__ entries, const unsigned* __restrict__ offsets,
    const unsigned* __restrict__ alloc, float* __restrict__ out)
{
    __shared__ float4 sA[CHUNK];        // fx, fy, fz, packed(cx0|cx1<<8|cy0<<16|cy1<<24)
    __shared__ int    sZ[CHUNK];        // cz0 | cz1<<8
    __shared__ float4 sO[4*CHUNK];      // MLP outputs, quad-planar [q][entry]

    int t  = blockIdx.x;
    int tx = t & (TPA-1), ty = (t >> 4) & (TPA-1), tz = t >> 8;
    int ox = tx * TW, oy = ty * TW, oz = tz * TW;

    int tid = threadIdx.x;
    // owned voxels: v0 = tid, v1 = tid + 256  (z differs by 4)
    int vx  = ox + (tid & 7);
    int vy  = oy + ((tid >> 3) & 7);
    int vz0 = oz + (tid >> 6);
    int vz1 = vz0 + 4;

    float accA[C_OUT], accB[C_OUT];
    #pragma unroll
    for (int c = 0; c < C_OUT; ++c) { accA[c] = 0.0f; accB[c] = 0.0f; }

    unsigned e0 = offsets[t], e1 = alloc[t];
    for (unsigned base = e0; base < e1; base += CHUNK) {
        int n = min((unsigned)CHUNK, e1 - base);
        if (tid < n) {
            unsigned p = entries[base + tid];
            float4 f = pf[p];
            unsigned key = __float_as_uint(f.w);
            int X = (int)(key & 511u) - 256;
            int Y = (int)((key >> 9) & 511u) - 256;
            int Z = (int)((key >> 18) & 511u) - 256;
            unsigned pk = (unsigned)clampi(X, GW-1)        |
                          ((unsigned)clampi(X+1, GW-1)<<8) |
                          ((unsigned)clampi(Y, GH-1)<<16)  |
                          ((unsigned)clampi(Y+1, GH-1)<<24);
            sA[tid] = make_float4(f.x, f.y, f.z, __uint_as_float(pk));
            sZ[tid] = clampi(Z, GD-1) | (clampi(Z+1, GD-1) << 8);
            #pragma unroll
            for (int q = 0; q < 4; ++q) sO[q*CHUNK + tid] = po[(size_t)q * M_PTS + p];
        }
        __syncthreads();

        for (int j = 0; j < n; ++j) {
            float4 a = sA[j];                       // uniform addr -> broadcast
            unsigned pk = __float_as_uint(a.w);
            int cx0 = pk & 255, cx1 = (pk >> 8) & 255;
            int cy0 = (pk >> 16) & 255, cy1 = pk >> 24;
            float wx = 0.0f, wy = 0.0f;
            bool hx = false, hy = false;
            if (vx == cx0) { wx += 1.0f - a.x; hx = true; }
            if (vx == cx1) { wx += a.x;        hx = true; }
            if (vy == cy0) { wy += 1.0f - a.y; hy = true; }
            if (vy == cy1) { wy += a.y;        hy = true; }
            if (hx & hy) {
                int pz = sZ[j];
                int cz0 = pz & 255, cz1 = (pz >> 8) & 255;
                float wzA = 0.0f, wzB = 0.0f;
                if (vz0 == cz0) wzA += 1.0f - a.z;
                if (vz0 == cz1) wzA += a.z;
                if (vz1 == cz0) wzB += 1.0f - a.z;
                if (vz1 == cz1) wzB += a.z;
                bool hz = ((vz0 == cz0) | (vz0 == cz1)) | ((vz1 == cz0) | (vz1 == cz1));
                if (hz) {
                    float wxy = wx * wy;
                    float wA = wxy * wzA, wB = wxy * wzB;   // 0 when that voxel misses
                    #pragma unroll
                    for (int q = 0; q < 4; ++q) {
                        float4 ov = sO[q*CHUNK + j];
                        accA[4*q+0] = fmaf(wA, ov.x, accA[4*q+0]);
                        accA[4*q+1] = fmaf(wA, ov.y, accA[4*q+1]);
                        accA[4*q+2] = fmaf(wA, ov.z, accA[4*q+2]);
                        accA[4*q+3] = fmaf(wA, ov.w, accA[4*q+3]);
                        accB[4*q+0] = fmaf(wB, ov.x, accB[4*q+0]);
                        accB[4*q+1] = fmaf(wB, ov.y, accB[4*q+1]);
                        accB[4*q+2] = fmaf(wB, ov.z, accB[4*q+2]);
                        accB[4*q+3] = fmaf(wB, ov.w, accB[4*q+3]);
                    }
                }
            }
        }
        __syncthreads();
    }

    // ---- dense register writeback (full coverage -> no memset needed) ----
    size_t baseA = ((((size_t)vz0) * GH + vy) * GW + vx) * C_OUT;
    size_t baseB = ((((size_t)vz1) * GH + vy) * GW + vx) * C_OUT;
    #pragma unroll
    for (int q = 0; q < 4; ++q) {
        *(float4*)(out + baseA + 4*q) = make_float4(accA[4*q+0], accA[4*q+1], accA[4*q+2], accA[4*q+3]);
        *(float4*)(out + baseB + 4*q) = make_float4(accB[4*q+0], accB[4*q+1], accB[4*q+2], accB[4*q+3]);
    }
}

// ============================================================================
// Fallback (round-3 fused kernel) if workspace is too small.
// ============================================================================
#define SEGS   8
#define SEGLEN (NSAMP / SEGS)
#define NTHREADS (N_RAYS * SEGS)

__global__ __launch_bounds__(256, 2) void splat_seg_kernel(
    const float* __restrict__ origins, const float* __restrict__ dirs,
    const float* __restrict__ nearv,   const float* __restrict__ farv,
    const float* __restrict__ enc,     const int*   __restrict__ gidx,
    const float* __restrict__ grid,    const float* __restrict__ W0,
    const float* __restrict__ b0,      const float* __restrict__ W1,
    const float* __restrict__ b1,      float* __restrict__ out)
{
    int tid = blockIdx.x * blockDim.x + threadIdx.x;
    if (tid >= NTHREADS) return;
    int ray = tid / SEGS;
    int seg = tid - ray * SEGS;
    float nr = nearv[ray], fr = farv[ray];
    float ox = origins[3*ray+0], oy = origins[3*ray+1], oz = origins[3*ray+2];
    float rdx = dirs[3*ray+0],   rdy = dirs[3*ray+1],   rdz = dirs[3*ray+2];
    int   b  = gidx[ray];
    float accv[8][C_OUT];
    #pragma unroll
    for (int sl = 0; sl < 8; ++sl)
        #pragma unroll
        for (int c = 0; c < C_OUT; ++c) accv[sl][c] = 0.0f;
    int Xp = 0, Yp = 0, Zp = 0;
    #pragma unroll 1
    for (int k = 0; k < SEGLEN; ++k) {
        int s = seg * SEGLEN + k;
        float t  = nr + (fr - nr) * ((float)s * (1.0f / (NSAMP - 1)));
        float px = fmaf(t, rdx, ox);
        float py = fmaf(t, rdy, oy);
        float pz = fmaf(t, rdz, oz);
        float cx = ((px + 1.0f) * (float)GW - 1.0f) * 0.5f;
        float cy = ((py + 1.0f) * (float)GH - 1.0f) * 0.5f;
        float cz = ((pz + 1.0f) * (float)GD - 1.0f) * 0.5f;
        float fxf = floorf(cx), fyf = floorf(cy), fzf = floorf(cz);
        float fx = cx - fxf, fy = cy - fyf, fz = cz - fzf;
        int X = (int)fxf, Y = (int)fyf, Z = (int)fzf;
        if (k == 0) { Xp = X; Yp = Y; Zp = Z; }
        else if (X != Xp || Y != Yp || Z != Zp) {
            bool fXm[2], fYm[2], fZm[2];
            int  vx[2], vy[2], vz[2];
            #pragma unroll
            for (int p = 0; p < 2; ++p) {
                int xo = Xp + ((Xp ^ p) & 1), xn = X + ((X ^ p) & 1);
                fXm[p] = (xo != xn);  vx[p] = clampi(xo, GW-1);
                int yo = Yp + ((Yp ^ p) & 1), yn = Y + ((Y ^ p) & 1);
                fYm[p] = (yo != yn);  vy[p] = clampi(yo, GH-1);
                int zo = Zp + ((Zp ^ p) & 1), zn = Z + ((Z ^ p) & 1);
                fZm[p] = (zo != zn);  vz[p] = clampi(zo, GD-1);
            }
            #pragma unroll
            for (int pxi = 0; pxi < 2; ++pxi)
            #pragma unroll
            for (int pyi = 0; pyi < 2; ++pyi)
            #pragma unroll
            for (int pzi = 0; pzi < 2; ++pzi) {
                const int sl = pxi*4 + pyi*2 + pzi;
                if (fXm[pxi] | fYm[pyi] | fZm[pzi]) {
                    size_t flat = ((((size_t)b * GD + vz[pzi]) * GH + vy[pyi]) * GW + vx[pxi]) * C_OUT;
                    float* op = out + flat;
                    #pragma unroll
                    for (int c = 0; c < C_OUT; ++c) { atomicAdd(op + c, accv[sl][c]); accv[sl][c] = 0.0f; }
                }
            }
            Xp = X; Yp = Y; Zp = Z;
        }
        float feat[C_IN];
        {
            const float4* e4 = (const float4*)(enc + (size_t)ray * C_IN);
            #pragma unroll
            for (int q = 0; q < C_IN/4; ++q) {
                float4 v = e4[q];
                feat[4*q+0] = v.x; feat[4*q+1] = v.y; feat[4*q+2] = v.z; feat[4*q+3] = v.w;
            }
        }
        int gx[2] = { clampi(X, GW-1), clampi(X+1, GW-1) };
        int gy[2] = { clampi(Y, GH-1), clampi(Y+1, GH-1) };
        int gz[2] = { clampi(Z, GD-1), clampi(Z+1, GD-1) };
        float wxa[2] = { 1.0f - fx, fx };
        float wya[2] = { 1.0f - fy, fy };
        float wza[2] = { 1.0f - fz, fz };
        #pragma unroll
        for (int dz = 0; dz < 2; ++dz)
        #pragma unroll
        for (int dy = 0; dy < 2; ++dy)
        #pragma unroll
        for (int dx = 0; dx < 2; ++dx) {
            float w = wza[dz] * wya[dy] * wxa[dx];
            size_t flat = ((((size_t)b * GD + gz[dz]) * GH + gy[dy]) * GW + gx[dx]) * C_IN;
            const float4* g4 = (const float4*)(grid + flat);
            #pragma unroll
            for (int q = 0; q < C_IN/4; ++q) {
                float4 v = g4[q];
                feat[4*q+0] = fmaf(w, v.x, feat[4*q+0]);
                feat[4*q+1] = fmaf(w, v.y, feat[4*q+1]);
                feat[4*q+2] = fmaf(w, v.z, feat[4*q+2]);
                feat[4*q+3] = fmaf(w, v.w, feat[4*q+3]);
            }
        }
        float h[C_HID];
        #pragma unroll
        for (int j = 0; j < C_HID; ++j) h[j] = b0[j];
        #pragma unroll
        for (int i = 0; i < C_IN; ++i) {
            float xi = feat[i];
            #pragma unroll
            for (int j = 0; j < C_HID; ++j) h[j] = fmaf(xi, W0[i*C_HID + j], h[j]);
        }
        #pragma unroll
        for (int j = 0; j < C_HID; ++j) h[j] = fmaxf(h[j], 0.0f);
        float o[C_OUT];
        #pragma unroll
        for (int j = 0; j < C_OUT; ++j) o[j] = b1[j];
        #pragma unroll
        for (int i = 0; i < C_HID; ++i) {
            float hi = h[i];
            #pragma unroll
            for (int j = 0; j < C_OUT; ++j) o[j] = fmaf(hi, W1[i*C_OUT + j], o[j]);
        }
        float wxs[2], wys[2], wzs[2];
        #pragma unroll
        for (int p = 0; p < 2; ++p) {
            wxs[p] = ((X & 1) == p) ? (1.0f - fx) : fx;
            wys[p] = ((Y & 1) == p) ? (1.0f - fy) : fy;
            wzs[p] = ((Z & 1) == p) ? (1.0f - fz) : fz;
        }
        #pragma unroll
        for (int pxi = 0; pxi < 2; ++pxi)
        #pragma unroll
        for (int pyi = 0; pyi < 2; ++pyi)
        #pragma unroll
        for (int pzi = 0; pzi < 2; ++pzi) {
            const int sl = pxi*4 + pyi*2 + pzi;
            float w = wxs[pxi] * wys[pyi] * wzs[pzi];
            #pragma unroll
            for (int c = 0; c < C_OUT; ++c) accv[sl][c] = fmaf(w, o[c], accv[sl][c]);
        }
    }
    #pragma unroll
    for (int pxi = 0; pxi < 2; ++pxi)
    #pragma unroll
    for (int pyi = 0; pyi < 2; ++pyi)
    #pragma unroll
    for (int pzi = 0; pzi < 2; ++pzi) {
        const int sl = pxi*4 + pyi*2 + pzi;
        int vx = clampi(Xp + ((Xp ^ pxi) & 1), GW-1);
        int vy = clampi(Yp + ((Yp ^ pyi) & 1), GH-1);
        int vz = clampi(Zp + ((Zp ^ pzi) & 1), GD-1);
        size_t flat = ((((size_t)b * GD + vz) * GH + vy) * GW + vx) * C_OUT;
        float* op = out + flat;
        #pragma unroll
        for (int c = 0; c < C_OUT; ++c) atomicAdd(op + c, accv[sl][c]);
    }
}

// ============================================================================
extern "C" void kernel_launch(void* const* d_in, const int* in_sizes, int n_in,
                              void* d_out, int out_size, void* d_ws, size_t ws_size,
                              hipStream_t stream) {
    const float* origins = (const float*)d_in[0];
    const float* dirs    = (const float*)d_in[1];
    const float* nearv   = (const float*)d_in[2];
    const float* farv    = (const float*)d_in[3];
    const float* enc     = (const float*)d_in[4];
    const int*   gidx    = (const int*)  d_in[5];
    const float* grid    = (const float*)d_in[6];
    const float* W0      = (const float*)d_in[7];
    const float* b0      = (const float*)d_in[8];
    const float* W1      = (const float*)d_in[9];
    const float* b1      = (const float*)d_in[10];
    float* out = (float*)d_out;

    const size_t PF_B = (size_t)M_PTS * 16;         // 25,165,824
    const size_t PO_B = (size_t)M_PTS * 64;         // 100,663,296
    const size_t EN_B = (size_t)M_PTS * 8 * 4;      // 50,331,648 (hard bound)
    const size_t CT_B = (size_t)NTILES * 4;
    const size_t NEED = PF_B + PO_B + EN_B + 3 * CT_B;

    if (ws_size < NEED) {
        // fallback: fused register-merged scatter (round-3 path)
        hipMemsetAsync(out, 0, (size_t)out_size * sizeof(float), stream);
        splat_seg_kernel<<<NTHREADS/256, 256, 0, stream>>>(
            origins, dirs, nearv, farv, enc, gidx, grid, W0, b0, W1, b1, out);
        return;
    }

    char* w = (char*)d_ws;
    float4*   pf      = (float4*)   w;              w += PF_B;
    float4*   po      = (float4*)   w;              w += PO_B;
    unsigned* entries = (unsigned*) w;              w += EN_B;
    unsigned* counts  = (unsigned*) w;              w += CT_B;
    unsigned* offsets = (unsigned*) w;              w += CT_B;
    unsigned* alloc   = (unsigned*) w;              w += CT_B;

    hipMemsetAsync(counts, 0, CT_B, stream);
    k1_point<<<M_PTS/256, 256, 0, stream>>>(origins, dirs, nearv, farv, enc, gidx,
                                            grid, W0, b0, W1, b1, pf, po, counts);
    k2_scan<<<1, 256, 0, stream>>>(counts, offsets, alloc);
    k3_scatter<<<M_PTS/256, 256, 0, stream>>>(pf, alloc, entries);
    k4_accum<<<NTILES, 256, 0, stream>>>(pf, po, entries, offsets, alloc, out);
    // K4 writes every output voxel densely -> no output memset needed.
}